// Round 3
// baseline (390.674 us; speedup 1.0000x reference)
//
#include <hip/hip_runtime.h>
#include <math.h>

// FFT convolution: y[b,d,:] = (h[d] (*) x[b,d])[0:L] + x[b,d,:]*B[d]
// N=8192 packed-complex FFT per row in 64KB LDS. Register-blocked
// 4-stage passes, twiddles via one sincos + squaring chain, XOR bank
// swizzle (closed-form per pass), two-kernel split (H spectra in d_ws),
// fused ends (global->regs->stage1, last inv pass -> y store, x in regs).
// R(this): complex values as ext_vector<float,2> so add/sub lower to
// v_pk_add_f32/v_pk_sub_f32 (compiler-packed, gfx90a+ packed-FP32);
// cmul stays SCALAR (2 mul + 2 fma). R2's op_sel inline-asm cmul was
// numerically wrong on gfx950 (op_sel on v_pk_*_f32 not honored as
// assumed -> absmax 740); do not reintroduce without an isolated probe.
// Butterfly core 8 -> 6 VALU instrs.

#define FFT_N  8192
#define SEQ_L  8192
#define DIM_D  1024
#define NTHR   512

typedef float v2f __attribute__((ext_vector_type(2)));

__device__ __forceinline__ v2f mk(float a, float b){ v2f r; r.x = a; r.y = b; return r; }
__device__ __forceinline__ v2f cadd(v2f a, v2f b){ return a + b; }   // v_pk_add_f32
__device__ __forceinline__ v2f csub(v2f a, v2f b){ return a - b; }   // v_pk_add_f32 neg
// complex multiply: scalar 2 mul + 2 fma (known-good numerics)
__device__ __forceinline__ v2f cmul(v2f a, v2f b){
    return mk(a.x*b.x - a.y*b.y, a.x*b.y + a.y*b.x);
}
__device__ __forceinline__ int rev13(int k){ return (int)(__brev((unsigned)k) >> 19); }
// bank-conflict swizzle: spread bank-pair (i&15) with higher bits. bijective.
__device__ __forceinline__ int SW(int i){ return i ^ ((i >> 5) & 15) ^ ((i >> 9) & 15); }

// tw = exp(-i*m*pi/8) * w (DIF), trivial m folded
__device__ __forceinline__ v2f tw8_dif(int m, v2f w){
    constexpr float c[8] = {1.f, 0.92387953251f, 0.70710678119f, 0.38268343236f, 0.f, -0.38268343236f, -0.70710678119f, -0.92387953251f};
    constexpr float s[8] = {0.f, -0.38268343236f, -0.70710678119f, -0.92387953251f, -1.f, -0.92387953251f, -0.70710678119f, -0.38268343236f};
    if (m == 0) return w;
    if (m == 4) return mk(w.y, -w.x);            // (-i)*w
    return cmul(mk(c[m], s[m]), w);
}
// tw = exp(+i*m*pi/8) * w (DIT)
__device__ __forceinline__ v2f tw8_dit(int m, v2f w){
    constexpr float c[8] = {1.f, 0.92387953251f, 0.70710678119f, 0.38268343236f, 0.f, -0.38268343236f, -0.70710678119f, -0.92387953251f};
    constexpr float s[8] = {0.f, 0.38268343236f, 0.70710678119f, 0.92387953251f, 1.f, 0.92387953251f, 0.70710678119f, 0.38268343236f};
    if (m == 0) return w;
    if (m == 4) return mk(-w.y, w.x);            // (+i)*w
    return cmul(mk(c[m], s[m]), w);
}

// ---- DIF stage over bit3 of the owned 4 bits (8 butterflies)
__device__ __forceinline__ void dif_stage8(v2f v[16], v2f w){
    #pragma unroll
    for (int m = 0; m < 8; ++m){
        v2f tw = tw8_dif(m, w);
        v2f u = v[m], t = v[m+8];
        v[m] = cadd(u,t);
        v[m+8] = cmul(csub(u,t), tw);
    }
}

// ---- remaining 3 DIF stages; w here is base^2
__device__ __forceinline__ void dif_tail3(v2f v[16], v2f w){
    {   // stage over bit2: c4 twiddles * w, hoisted
        v2f t0 = w;
        v2f t1 = cmul(mk(0.70710678119f, -0.70710678119f), w);
        v2f t2 = mk(w.y, -w.x);
        v2f t3 = cmul(mk(-0.70710678119f, -0.70710678119f), w);
        #pragma unroll
        for (int h = 0; h < 16; h += 8){
            { v2f u=v[h+0], t=v[h+4]; v[h+0]=cadd(u,t); v[h+4]=cmul(csub(u,t), t0); }
            { v2f u=v[h+1], t=v[h+5]; v[h+1]=cadd(u,t); v[h+5]=cmul(csub(u,t), t1); }
            { v2f u=v[h+2], t=v[h+6]; v[h+2]=cadd(u,t); v[h+6]=cmul(csub(u,t), t2); }
            { v2f u=v[h+3], t=v[h+7]; v[h+3]=cadd(u,t); v[h+7]=cmul(csub(u,t), t3); }
        }
    }
    w = cmul(w,w);
    #pragma unroll
    for (int q = 0; q < 16; q += 4){
        { v2f u=v[q+0], t=v[q+2]; v[q+0]=cadd(u,t); v[q+2]=cmul(csub(u,t), w); }
        { v2f u=v[q+1], t=v[q+3]; v2f tw=mk(w.y,-w.x);
          v[q+1]=cadd(u,t); v[q+3]=cmul(csub(u,t), tw); }
    }
    w = cmul(w,w);
    #pragma unroll
    for (int e = 0; e < 16; e += 2){
        v2f u=v[e], t=v[e+1];
        v[e]=cadd(u,t); v[e+1]=cmul(csub(u,t), w);
    }
}

__device__ __forceinline__ void dif_pass4(v2f v[16], v2f w){
    dif_stage8(v, w);
    dif_tail3(v, cmul(w,w));
}

// ---- 4 radix-2 DIT (inverse, +i) stages in registers.
__device__ __forceinline__ void dit_pass4(v2f v[16], v2f w3){
    v2f w2 = cmul(w3,w3), w1 = cmul(w2,w2), w0 = cmul(w1,w1);
    #pragma unroll
    for (int e = 0; e < 16; e += 2){
        v2f t = cmul(v[e+1], w0);
        v2f u = v[e];
        v[e] = cadd(u,t); v[e+1] = csub(u,t);
    }
    #pragma unroll
    for (int q = 0; q < 16; q += 4){
        { v2f t = cmul(v[q+2], w1); v2f u=v[q+0]; v[q+0]=cadd(u,t); v[q+2]=csub(u,t); }
        { v2f tw = mk(-w1.y, w1.x);          // (+i)*w1
          v2f t = cmul(v[q+3], tw); v2f u=v[q+1]; v[q+1]=cadd(u,t); v[q+3]=csub(u,t); }
    }
    {   v2f t0 = w2;
        v2f t1 = cmul(mk(0.70710678119f, 0.70710678119f), w2);
        v2f t2 = mk(-w2.y, w2.x);
        v2f t3 = cmul(mk(-0.70710678119f, 0.70710678119f), w2);
        #pragma unroll
        for (int h = 0; h < 16; h += 8){
            { v2f t=cmul(v[h+4], t0); v2f u=v[h+0]; v[h+0]=cadd(u,t); v[h+4]=csub(u,t); }
            { v2f t=cmul(v[h+5], t1); v2f u=v[h+1]; v[h+1]=cadd(u,t); v[h+5]=csub(u,t); }
            { v2f t=cmul(v[h+6], t2); v2f u=v[h+2]; v[h+2]=cadd(u,t); v[h+6]=csub(u,t); }
            { v2f t=cmul(v[h+7], t3); v2f u=v[h+3]; v[h+3]=cadd(u,t); v[h+7]=csub(u,t); }
        }
    }
    #pragma unroll
    for (int m = 0; m < 8; ++m){
        v2f tw = tw8_dit(m, w3);
        v2f t = cmul(v[m+8], tw);
        v2f u = v[m];
        v[m] = cadd(u,t); v[m+8] = csub(u,t);
    }
}

// forward stages 0..11, pass 1 fused with the global load (zero pad folded).
// Swizzle closed forms:
//   pass A (stride 512): SW((k<<9)|tid)        = (k<<9) | (T1 ^ k),  T1 = tid ^ ((tid>>5)&15)
//   pass B (stride 32):  SW((hi<<9)|(k<<5)|lo) = (hi<<9)|(k<<5)|(TB ^ k), TB = lo ^ hi
//   pass C (stride 2):   SW((h2<<5)|(k<<1)|b0) = (h2<<5) | (((k<<1)|b0) ^ M3), M3 = (h2 ^ (h2>>4)) & 15
template<bool SAVEX>
__device__ __forceinline__ void fwd_fft12_fused(v2f* z, const v2f* __restrict__ row,
                                                int tid, v2f* xs){
    v2f v[16];
    float sn, cs;
    __sincosf(-(float)M_PI * (float)tid * (1.0f/4096.0f), &sn, &cs);
    v2f w = mk(cs, sn);
    const int T1 = tid ^ ((tid >> 5) & 15);
    #pragma unroll
    for (int k = 0; k < 8; ++k){
        v[k] = row[(k<<9) | tid];
        if (SAVEX) xs[k] = v[k];
    }
    // stage 1 with zero top half: upper arm = v[m]*tw, lower arm unchanged
    #pragma unroll
    for (int m = 0; m < 8; ++m) v[m+8] = cmul(v[m], tw8_dif(m, w));
    dif_tail3(v, cmul(w,w));
    #pragma unroll
    for (int k = 0; k < 16; ++k) z[(k<<9) | (T1 ^ k)] = v[k];
    __syncthreads();

    const int hi = tid >> 5, lo = tid & 31;
    const int baseB = hi << 9, TB = lo ^ hi;
    __sincosf(-(float)M_PI * (float)lo * (1.0f/256.0f), &sn, &cs);
    w = mk(cs, sn);
    #pragma unroll
    for (int k = 0; k < 16; ++k) v[k] = z[baseB | (k<<5) | (TB ^ k)];
    dif_pass4(v, w);
    #pragma unroll
    for (int k = 0; k < 16; ++k) z[baseB | (k<<5) | (TB ^ k)] = v[k];
    __syncthreads();

    const int h2 = tid >> 1, b0 = tid & 1;
    const int baseC = h2 << 5, M3 = (h2 ^ (h2 >> 4)) & 15;
    w = b0 ? mk(0.98078528040f, -0.19509032202f)   // exp(-i pi/16)
           : mk(1.f, 0.f);
    #pragma unroll
    for (int k = 0; k < 16; ++k) v[k] = z[baseC | (((k<<1)|b0) ^ M3)];
    dif_pass4(v, w);
    #pragma unroll
    for (int k = 0; k < 16; ++k) z[baseC | (((k<<1)|b0) ^ M3)] = v[k];
    __syncthreads();
}

// real-FFT untangle: from Z[rev(p)], Z[rev(N-p)] produce A=E+tO, G=E-tO
__device__ __forceinline__ void untangle(v2f zk, v2f znk, v2f t, v2f& A, v2f& G){
    v2f E  = mk(0.5f*(zk.x+znk.x), 0.5f*(zk.y-znk.y));
    v2f O  = mk(0.5f*(zk.y+znk.y), -0.5f*(zk.x-znk.x));
    v2f tO = cmul(t, O);
    A = cadd(E, tO); G = csub(E, tO);
}

// untangle x, multiply with H (Ah,Gh), repack packed-inverse spectrum pair
__device__ __forceinline__ void pointmul(v2f zk, v2f znk, v2f t,
                                         v2f Ah, v2f Gh, float invN,
                                         v2f& Wp, v2f& Wm){
    v2f Xp, Xm; untangle(zk, znk, t, Xp, Xm);
    v2f Cp = cmul(Ah, Xp), Cm = cmul(Gh, Xm);
    v2f S  = (Cp + Cm) * 0.5f;
    v2f Dd = (Cp - Cm) * 0.5f;
    v2f u  = mk(t.y*Dd.x - t.x*Dd.y, t.y*Dd.y + t.x*Dd.x); // i*conj(t)*Dd
    v2f wp = (S + u) * invN;
    v2f wm = (S - u) * invN;
    Wp = wp;
    Wm = mk(wm.x, -wm.y);
}

// ===================== kernel A: H spectra, once per d =====================
__global__ __launch_bounds__(NTHR)
void h_spec_kernel(const float* __restrict__ h,
                   float4* __restrict__ p0, float4* __restrict__ p1,
                   v2f* __restrict__ hs2)
{
    __shared__ v2f z[FFT_N];
    const int tid = (int)threadIdx.x;
    const int d   = (int)blockIdx.x;
    const v2f* hrow = (const v2f*)(h + (size_t)d * SEQ_L);

    v2f dummy[8];
    fwd_fft12_fused<false>(z, hrow, tid, dummy);

    const size_t base = (size_t)d * 2048;
    #pragma unroll
    for (int q = 0; q < 4; ++q){
        int g = tid + NTHR * q;
        v2f A1, G1, A2, G2;
        if (g == 0){
            v2f z0 = z[SW(0)], z1 = z[SW(1)], z2 = z[SW(2)], z3 = z[SW(3)];
            v2f Z0 = cadd(z0,z1), Z1 = csub(z0,z1), Z2 = cadd(z2,z3), Z3 = csub(z2,z3);
            v2f A3, G3;
            untangle(Z0, Z0, mk(1.f, 0.f), A1, G1);                        // p=0
            untangle(Z2, Z3, mk(0.70710678119f, -0.70710678119f), A2, G2); // p=2048
            untangle(Z1, Z1, mk(0.f, -1.f), A3, G3);                       // p=4096
            hs2[(size_t)d*2 + 0] = A3;
            hs2[(size_t)d*2 + 1] = G3;
        } else {
            int a = rev13(g), c = rev13(4096 - g);
            v2f za = z[SW(a)], zb = z[SW(a+1)], zc = z[SW(c)], zd = z[SW(c+1)];
            v2f Z12a = cadd(za,zb), Z12b = csub(za,zb);
            v2f Z12c = cadd(zc,zd), Z12d = csub(zc,zd);
            float sn, cs; __sincosf(-(float)M_PI * (float)g * (1.0f/8192.0f), &sn, &cs);
            v2f t1 = mk(cs, sn), t2 = mk(-sn, -cs);
            untangle(Z12a, Z12d, t1, A1, G1);   // pair (g, 8192-g)
            untangle(Z12c, Z12b, t2, A2, G2);   // pair (4096-g, 4096+g)
        }
        p0[base + q*NTHR + tid] = make_float4(A1.x, A1.y, G1.x, G1.y);
        p1[base + q*NTHR + tid] = make_float4(A2.x, A2.y, G2.x, G2.y);
    }
}

// ===================== kernel B: x FFT + pointwise + inverse =====================
__global__ __launch_bounds__(NTHR)
void fftconv_x_kernel(const float* __restrict__ x,
                      const float* __restrict__ Bv,
                      float* __restrict__ y,
                      const float4* __restrict__ p0, const float4* __restrict__ p1,
                      const v2f* __restrict__ hs2)
{
    __shared__ v2f z[FFT_N];
    const int tid = (int)threadIdx.x;
    const int d   = (int)blockIdx.x;
    const int b   = (int)blockIdx.y;

    const float Bd = Bv[d];
    const v2f* xrow = (const v2f*)(x + ((size_t)b * DIM_D + (size_t)d) * SEQ_L);
    v2f*       yrow = (v2f*)(y + ((size_t)b * DIM_D + (size_t)d) * SEQ_L);
    const float invN = 1.0f / (float)FFT_N;

    v2f xs[8];                       // x kept in regs for the epilogue (no HBM re-read)
    fwd_fft12_fused<true>(z, xrow, tid, xs);

    // fused middle: fwd stage12 + untangle + multiply + repack + inv stage0.
    const size_t base = (size_t)d * 2048;
    #pragma unroll
    for (int q = 0; q < 4; ++q){
        int g = tid + NTHR * q;
        float4 f0 = p0[base + q*NTHR + tid];
        float4 f1 = p1[base + q*NTHR + tid];
        v2f Ah1 = mk(f0.x, f0.y), Gh1 = mk(f0.z, f0.w);
        v2f Ah2 = mk(f1.x, f1.y), Gh2 = mk(f1.z, f1.w);
        if (g == 0){
            v2f A3 = hs2[(size_t)d*2 + 0], G3 = hs2[(size_t)d*2 + 1];
            v2f z0 = z[SW(0)], z1 = z[SW(1)], z2 = z[SW(2)], z3 = z[SW(3)];
            v2f Z0 = cadd(z0,z1), Z1 = csub(z0,z1), Z2 = cadd(z2,z3), Z3 = csub(z2,z3);
            v2f W0, W0b, W1, W1b, W2, W3;
            pointmul(Z0, Z0, mk(1.f, 0.f),  Ah1, Gh1, invN, W0, W0b);
            pointmul(Z1, Z1, mk(0.f, -1.f), A3,  G3,  invN, W1, W1b);
            pointmul(Z2, Z3, mk(0.70710678119f, -0.70710678119f), Ah2, Gh2, invN, W2, W3);
            z[SW(0)] = cadd(W0, W1);
            z[SW(1)] = csub(W0, W1);
            z[SW(2)] = cadd(W2, W3);
            z[SW(3)] = csub(W2, W3);
        } else {
            int a = rev13(g), c = rev13(4096 - g);
            v2f za = z[SW(a)], zb = z[SW(a+1)], zc = z[SW(c)], zd = z[SW(c+1)];
            v2f Z12a = cadd(za,zb), Z12b = csub(za,zb);
            v2f Z12c = cadd(zc,zd), Z12d = csub(zc,zd);
            float sn, cs; __sincosf(-(float)M_PI * (float)g * (1.0f/8192.0f), &sn, &cs);
            v2f t1 = mk(cs, sn), t2 = mk(-sn, -cs);
            v2f Wp1, Wm1, Wp2, Wm2;
            pointmul(Z12a, Z12d, t1, Ah1, Gh1, invN, Wp1, Wm1);
            pointmul(Z12c, Z12b, t2, Ah2, Gh2, invN, Wp2, Wm2);
            z[SW(a)]   = cadd(Wp1, Wm2);
            z[SW(a+1)] = csub(Wp1, Wm2);
            z[SW(c)]   = cadd(Wp2, Wm1);
            z[SW(c+1)] = csub(Wp2, Wm1);
        }
    }
    __syncthreads();

    // inverse stages 1..12; last pass fused with the y-store
    {
        v2f v[16];
        float sn, cs;
        const int h2 = tid >> 1, b0 = tid & 1, hi = tid >> 5, lo = tid & 31;
        const int baseC = h2 << 5, M3 = (h2 ^ (h2 >> 4)) & 15;
        v2f w3 = b0 ? mk(0.98078528040f, 0.19509032202f)  // exp(+i pi/16)
                    : mk(1.f, 0.f);
        #pragma unroll
        for (int k = 0; k < 16; ++k) v[k] = z[baseC | (((k<<1)|b0) ^ M3)];
        dit_pass4(v, w3);
        #pragma unroll
        for (int k = 0; k < 16; ++k) z[baseC | (((k<<1)|b0) ^ M3)] = v[k];
        __syncthreads();
        const int baseB = hi << 9, TB = lo ^ hi;
        __sincosf((float)M_PI * (float)lo * (1.0f/256.0f), &sn, &cs);
        w3 = mk(cs, sn);
        #pragma unroll
        for (int k = 0; k < 16; ++k) v[k] = z[baseB | (k<<5) | (TB ^ k)];
        dit_pass4(v, w3);
        #pragma unroll
        for (int k = 0; k < 16; ++k) z[baseB | (k<<5) | (TB ^ k)] = v[k];
        __syncthreads();
        const int T1 = tid ^ ((tid >> 5) & 15);
        __sincosf((float)M_PI * (float)tid * (1.0f/4096.0f), &sn, &cs);
        w3 = mk(cs, sn);
        #pragma unroll
        for (int k = 0; k < 16; ++k) v[k] = z[(k<<9) | (T1 ^ k)];
        dit_pass4(v, w3);
        #pragma unroll
        for (int k = 0; k < 8; ++k){
            int n = (k<<9) | tid;
            yrow[n] = v[k] + xs[k] * Bd;          // packed fma
        }
    }
}

// ============== fallback: single fused kernel (if ws too small) ==============
__global__ __launch_bounds__(NTHR)
void fftconv_fused(const float* __restrict__ h,
                   const float* __restrict__ x,
                   const float* __restrict__ Bv,
                   float* __restrict__ y)
{
    __shared__ v2f z[FFT_N];
    const int tid = (int)threadIdx.x;
    const int d   = (int)blockIdx.x;
    const int b   = (int)blockIdx.y;

    const float Bd = Bv[d];
    const v2f* hrow = (const v2f*)(h + (size_t)d * SEQ_L);
    const v2f* xrow = (const v2f*)(x + ((size_t)b * DIM_D + (size_t)d) * SEQ_L);
    v2f*       yrow = (v2f*)(y + ((size_t)b * DIM_D + (size_t)d) * SEQ_L);
    const float invN = 1.0f / (float)FFT_N;

    v2f dummy[8];
    fwd_fft12_fused<false>(z, hrow, tid, dummy);

    v2f Ah1[4], Gh1[4], Ah2[4], Gh2[4], Ah3, Gh3;
    #pragma unroll
    for (int q = 0; q < 4; ++q){
        int g = tid + NTHR * q;
        if (g == 0){
            v2f z0 = z[SW(0)], z1 = z[SW(1)], z2 = z[SW(2)], z3 = z[SW(3)];
            v2f Z0 = cadd(z0,z1), Z1 = csub(z0,z1), Z2 = cadd(z2,z3), Z3 = csub(z2,z3);
            untangle(Z0, Z0, mk(1.f, 0.f), Ah1[0], Gh1[0]);
            untangle(Z2, Z3, mk(0.70710678119f, -0.70710678119f), Ah2[0], Gh2[0]);
            untangle(Z1, Z1, mk(0.f, -1.f), Ah3, Gh3);
        } else {
            int a = rev13(g), c = rev13(4096 - g);
            v2f za = z[SW(a)], zb = z[SW(a+1)], zc = z[SW(c)], zd = z[SW(c+1)];
            v2f Z12a = cadd(za,zb), Z12b = csub(za,zb);
            v2f Z12c = cadd(zc,zd), Z12d = csub(zc,zd);
            float sn, cs; __sincosf(-(float)M_PI * (float)g * (1.0f/8192.0f), &sn, &cs);
            v2f t1 = mk(cs, sn), t2 = mk(-sn, -cs);
            untangle(Z12a, Z12d, t1, Ah1[q], Gh1[q]);
            untangle(Z12c, Z12b, t2, Ah2[q], Gh2[q]);
        }
    }
    __syncthreads();

    fwd_fft12_fused<false>(z, xrow, tid, dummy);

    #pragma unroll
    for (int q = 0; q < 4; ++q){
        int g = tid + NTHR * q;
        if (g == 0){
            v2f z0 = z[SW(0)], z1 = z[SW(1)], z2 = z[SW(2)], z3 = z[SW(3)];
            v2f Z0 = cadd(z0,z1), Z1 = csub(z0,z1), Z2 = cadd(z2,z3), Z3 = csub(z2,z3);
            v2f W0, W0b, W1, W1b, W2, W3;
            pointmul(Z0, Z0, mk(1.f, 0.f),  Ah1[0], Gh1[0], invN, W0, W0b);
            pointmul(Z1, Z1, mk(0.f, -1.f), Ah3,    Gh3,    invN, W1, W1b);
            pointmul(Z2, Z3, mk(0.70710678119f, -0.70710678119f), Ah2[0], Gh2[0], invN, W2, W3);
            z[SW(0)] = cadd(W0, W1);
            z[SW(1)] = csub(W0, W1);
            z[SW(2)] = cadd(W2, W3);
            z[SW(3)] = csub(W2, W3);
        } else {
            int a = rev13(g), c = rev13(4096 - g);
            v2f za = z[SW(a)], zb = z[SW(a+1)], zc = z[SW(c)], zd = z[SW(c+1)];
            v2f Z12a = cadd(za,zb), Z12b = csub(za,zb);
            v2f Z12c = cadd(zc,zd), Z12d = csub(zc,zd);
            float sn, cs; __sincosf(-(float)M_PI * (float)g * (1.0f/8192.0f), &sn, &cs);
            v2f t1 = mk(cs, sn), t2 = mk(-sn, -cs);
            v2f Wp1, Wm1, Wp2, Wm2;
            pointmul(Z12a, Z12d, t1, Ah1[q], Gh1[q], invN, Wp1, Wm1);
            pointmul(Z12c, Z12b, t2, Ah2[q], Gh2[q], invN, Wp2, Wm2);
            z[SW(a)]   = cadd(Wp1, Wm2);
            z[SW(a+1)] = csub(Wp1, Wm2);
            z[SW(c)]   = cadd(Wp2, Wm1);
            z[SW(c+1)] = csub(Wp2, Wm1);
        }
    }
    __syncthreads();

    {
        v2f v[16];
        float sn, cs;
        const int h2 = tid >> 1, b0 = tid & 1, hi = tid >> 5, lo = tid & 31;
        const int baseC = h2 << 5, M3 = (h2 ^ (h2 >> 4)) & 15;
        v2f w3 = b0 ? mk(0.98078528040f, 0.19509032202f)
                    : mk(1.f, 0.f);
        #pragma unroll
        for (int k = 0; k < 16; ++k) v[k] = z[baseC | (((k<<1)|b0) ^ M3)];
        dit_pass4(v, w3);
        #pragma unroll
        for (int k = 0; k < 16; ++k) z[baseC | (((k<<1)|b0) ^ M3)] = v[k];
        __syncthreads();
        const int baseB = hi << 9, TB = lo ^ hi;
        __sincosf((float)M_PI * (float)lo * (1.0f/256.0f), &sn, &cs);
        w3 = mk(cs, sn);
        #pragma unroll
        for (int k = 0; k < 16; ++k) v[k] = z[baseB | (k<<5) | (TB ^ k)];
        dit_pass4(v, w3);
        #pragma unroll
        for (int k = 0; k < 16; ++k) z[baseB | (k<<5) | (TB ^ k)] = v[k];
        __syncthreads();
        const int T1 = tid ^ ((tid >> 5) & 15);
        __sincosf((float)M_PI * (float)tid * (1.0f/4096.0f), &sn, &cs);
        w3 = mk(cs, sn);
        #pragma unroll
        for (int k = 0; k < 16; ++k) v[k] = z[(k<<9) | (T1 ^ k)];
        dit_pass4(v, w3);
        #pragma unroll
        for (int k = 0; k < 8; ++k){
            int n = (k<<9) | tid;
            v2f xv = xrow[n];
            yrow[n] = v[k] + xv * Bd;
        }
    }
}

extern "C" void kernel_launch(void* const* d_in, const int* in_sizes, int n_in,
                              void* d_out, int out_size, void* d_ws, size_t ws_size,
                              hipStream_t stream) {
    const float* h  = (const float*)d_in[0];
    const float* x  = (const float*)d_in[1];
    const float* Bv = (const float*)d_in[2];
    float* y = (float*)d_out;

    const int bsz = out_size / (DIM_D * SEQ_L);   // = 4
    const size_t plane = (size_t)DIM_D * 2048;    // float4 elements per plane
    const size_t need  = plane * 2 * sizeof(float4) + (size_t)DIM_D * 2 * sizeof(v2f);

    if (ws_size >= need) {
        float4* p0 = (float4*)d_ws;
        float4* p1 = p0 + plane;
        v2f*   hs2 = (v2f*)(p1 + plane);
        hipLaunchKernelGGL(h_spec_kernel, dim3(DIM_D), dim3(NTHR), 0, stream, h, p0, p1, hs2);
        hipLaunchKernelGGL(fftconv_x_kernel, dim3(DIM_D, bsz), dim3(NTHR), 0, stream,
                           x, Bv, y, p0, p1, hs2);
    } else {
        hipLaunchKernelGGL(fftconv_fused, dim3(DIM_D, bsz), dim3(NTHR), 0, stream, h, x, Bv, y);
    }
}